// Round 5
// baseline (708.473 us; speedup 1.0000x reference)
//
#include <hip/hip_runtime.h>
#include <math.h>

#define TID ((int)threadIdx.x)
#define LANE (TID & 63)

// ---------- constants ----------
#define NB 1024
#define NSEG 14
#define INP 504
#define ED 128
#define HD 256
#define ROWS (NB * NSEG)          // rows per ensemble = 14336
#define NROWS (4 * ROWS)          // 57344

// =======================================================================
// wave helpers (R3-proven)
// =======================================================================
__device__ __forceinline__ float wsum1(float v) {
    #pragma unroll
    for (int off = 32; off; off >>= 1) v += __shfl_xor(v, off, 64);
    return v;
}

__device__ __forceinline__ float rdlane(float v, int l) {
    return __int_as_float(__builtin_amdgcn_readlane(__float_as_int(v), l));
}

template<int E>
__device__ __forceinline__ float wssx(const float* v) {  // sum_{j>=1} v_j^2
    float s = (LANE == 0) ? 0.f : v[0] * v[0];
    #pragma unroll
    for (int t = 1; t < E; ++t) s += v[t] * v[t];
    return wsum1(s);
}

template<int E>
__device__ __forceinline__ float wlinE(const float* x, const float* y) {  // Minkowski
    float s = (LANE == 0) ? -x[0] * y[0] : x[0] * y[0];
    #pragma unroll
    for (int t = 1; t < E; ++t) s += x[t] * y[t];
    return wsum1(s);
}

template<int E>
__device__ __forceinline__ float w_exp0(float* v) {      // projx(safe_expmap0(v))
    float ss = wssx<E>(v);
    float n  = sqrtf(fmaxf(ss, 1e-12f));
    float th = fminf(n, 10.0f);
    float sc = sinhf(th) / n;
    #pragma unroll
    for (int t = 0; t < E; ++t) v[t] *= sc;
    float ss2 = sc * sc * ss;
    if (LANE == 0) v[0] = sqrtf(1.0f + ss2);
    return ss2;
}

template<int E>
__device__ __forceinline__ void w_log0k(float* v, float ss2) {  // logmap0, known ss2
    float x0 = sqrtf(1.0f + ss2);
    float d  = acoshf(fmaxf(x0, 1.0f + 1e-7f));
    float sc = d / sqrtf(fmaxf(ss2, 1e-12f));
    #pragma unroll
    for (int t = 0; t < E; ++t) v[t] *= sc;
    if (LANE == 0) v[0] = 0.f;
}

template<int E>
__device__ __forceinline__ void w_log0(float* v) {
    float ss = wssx<E>(v);
    float x0 = __shfl(v[0], 0, 64);
    float d  = acoshf(fmaxf(x0, 1.0f + 1e-7f));
    float sc = d / sqrtf(fmaxf(ss, 1e-12f));
    #pragma unroll
    for (int t = 0; t < E; ++t) v[t] *= sc;
    if (LANE == 0) v[0] = 0.f;
}

// =======================================================================
// K_prep_stats (R3-proven)
// =======================================================================
__global__ __launch_bounds__(256) void k_prep_stats(
    const float* __restrict__ i0, const float* __restrict__ i1,
    const float* __restrict__ i2, const float* __restrict__ i3,
    const float* __restrict__ esc, float* __restrict__ rowAB)
{
    int row = blockIdx.x * 4 + (TID >> 6);
    int e = row / ROWS;
    int r = row - e * ROWS;
    const float* src = (e == 0 ? i0 : e == 1 ? i1 : e == 2 ? i2 : i3) + (size_t)r * INP;

    float x[8];
    #pragma unroll
    for (int t = 0; t < 7; ++t) x[t] = src[64 * t + LANE];
    x[7] = (LANE < 56) ? src[448 + LANE] : 0.f;

    float s = 0.f;
    #pragma unroll
    for (int t = 0; t < 8; ++t) s += x[t];
    s = wsum1(s);
    float mu = s * (1.0f / 504.0f);
    #pragma unroll
    for (int t = 0; t < 7; ++t) x[t] -= mu;
    x[7] = (LANE < 56) ? x[7] - mu : 0.f;

    float ss = 0.f;
    #pragma unroll
    for (int t = 0; t < 8; ++t) ss += x[t] * x[t];
    ss = wsum1(ss);
    float sd  = sqrtf(ss * (1.0f / 503.0f)) + 1e-6f;
    float inv = tanhf(esc[0]) / sd;

    float x0c = __shfl(x[0], 0, 64);
    float e2 = (ss - x0c * x0c) * inv * inv;
    float n  = sqrtf(fmaxf(e2, 1e-12f));
    float th = fminf(n, 10.0f);
    float sc1 = sinhf(th) / n;
    float e3 = sc1 * sc1 * e2;
    float h0 = sqrtf(1.0f + e3);
    float d  = acoshf(fmaxf(h0, 1.0f + 1e-7f));
    float sc2 = d / sqrtf(fmaxf(e3, 1e-12f));
    float A = inv * sc1 * sc2;
    float B = -mu * A;
    if (LANE == 0) {
        rowAB[2 * row]     = A;
        rowAB[2 * row + 1] = B;
    }
}

// =======================================================================
// Tiled f32 GEMM (R3-proven, plain bias epilogue). KC tuned for occupancy.
// =======================================================================
template<int K, int KC, bool PREP>
__global__ __launch_bounds__(256) void k_gemm(
    const float* __restrict__ U,
    const float* __restrict__ i0, const float* __restrict__ i1,
    const float* __restrict__ i2, const float* __restrict__ i3,
    const float* __restrict__ rowAB,
    const float* __restrict__ Wg, const float* __restrict__ bg,
    float* __restrict__ Y)
{
    __shared__ float Ut[64][KC];
    __shared__ float Wt[KC][128];
    __shared__ float sA[64], sB[64];

    int row0 = blockIdx.x * 64;
    int e = row0 / ROWS;
    const float* Wp = Wg + (size_t)e * K * 128;

    const float* srcp;
    int rbase;
    if (PREP) {
        srcp = (e == 0 ? i0 : e == 1 ? i1 : e == 2 ? i2 : i3);
        rbase = row0 - e * ROWS;
        if (TID < 64) {
            sA[TID] = rowAB[2 * (row0 + TID)];
            sB[TID] = rowAB[2 * (row0 + TID) + 1];
        }
    } else {
        srcp = U;
        rbase = row0;
    }

    int tc = (TID & 31) * 4;
    int tr = (TID >> 5) * 8;
    float acc[8][4] = {};

    for (int kc = 0; kc < K; kc += KC) {
        __syncthreads();
        for (int idx = TID; idx < 64 * (KC / 4); idx += 256) {
            int r  = idx / (KC / 4);
            int kq = idx - r * (KC / 4);
            float4 v = *(const float4*)&srcp[(size_t)(rbase + r) * K + kc + kq * 4];
            if (PREP) {
                float a = sA[r], bb = sB[r];
                v.x = v.x * a + bb; v.y = v.y * a + bb;
                v.z = v.z * a + bb; v.w = v.w * a + bb;
                if (kc == 0 && kq == 0) v.x = 0.f;
            }
            *(float4*)&Ut[r][kq * 4] = v;
        }
        for (int idx = TID; idx < KC * 32; idx += 256) {
            int k = idx >> 5;
            int c = (idx & 31) * 4;
            *(float4*)&Wt[k][c] = *(const float4*)&Wp[(size_t)(kc + k) * 128 + c];
        }
        __syncthreads();
        for (int k = 0; k < KC; k += 4) {
            float4 b0 = *(const float4*)&Wt[k + 0][tc];
            float4 b1 = *(const float4*)&Wt[k + 1][tc];
            float4 b2 = *(const float4*)&Wt[k + 2][tc];
            float4 b3 = *(const float4*)&Wt[k + 3][tc];
            #pragma unroll
            for (int i = 0; i < 8; ++i) {
                float4 a = *(const float4*)&Ut[tr + i][k];
                acc[i][0] += a.x * b0.x; acc[i][1] += a.x * b0.y; acc[i][2] += a.x * b0.z; acc[i][3] += a.x * b0.w;
                acc[i][0] += a.y * b1.x; acc[i][1] += a.y * b1.y; acc[i][2] += a.y * b1.z; acc[i][3] += a.y * b1.w;
                acc[i][0] += a.z * b2.x; acc[i][1] += a.z * b2.y; acc[i][2] += a.z * b2.z; acc[i][3] += a.z * b2.w;
                acc[i][0] += a.w * b3.x; acc[i][1] += a.w * b3.y; acc[i][2] += a.w * b3.z; acc[i][3] += a.w * b3.w;
            }
        }
    }

    float4 bias = *(const float4*)&bg[e * 128 + tc];
    #pragma unroll
    for (int i = 0; i < 8; ++i) {
        float4 o;
        o.x = acc[i][0] + bias.x; o.y = acc[i][1] + bias.y;
        o.z = acc[i][2] + bias.z; o.w = acc[i][3] + bias.w;
        *(float4*)&Y[(size_t)(row0 + tr + i) * 128 + tc] = o;
    }
}

// =======================================================================
// inter-GEMM row chains (R3-proven)
// =======================================================================
__global__ __launch_bounds__(256) void k_mid(float* __restrict__ Y) {
    int row = blockIdx.x * 4 + (TID >> 6);
    size_t base = (size_t)row * 128;
    float v[2] = { Y[base + LANE], Y[base + 64 + LANE] };
    float ss2 = w_exp0<2>(v);
    w_log0k<2>(v, ss2);
    ss2 = w_exp0<2>(v);
    w_log0k<2>(v, ss2);
    Y[base + LANE] = v[0]; Y[base + 64 + LANE] = v[1];
}

__global__ __launch_bounds__(256) void k_post(float* __restrict__ Y) {
    int row = blockIdx.x * 4 + (TID >> 6);
    size_t base = (size_t)row * 128;
    float v[2] = { Y[base + LANE], Y[base + 64 + LANE] };
    w_exp0<2>(v);
    Y[base + LANE] = v[0]; Y[base + 64 + LANE] = v[1];
}

// =======================================================================
// frechet mean (R3-proven)
// =======================================================================
template<int NPTS>
__global__ __launch_bounds__(256) void k_frechet_w(
    const float* __restrict__ src, size_t blk_stride, size_t p_stride,
    float* __restrict__ dst)
{
    int prob = blockIdx.x * 4 + (TID >> 6);
    const float* base = src + (size_t)prob * blk_stride;
    float pa[NPTS], pb[NPTS];
    #pragma unroll
    for (int p = 0; p < NPTS; ++p) {
        pa[p] = base[(size_t)p * p_stride + LANE];
        pb[p] = base[(size_t)p * p_stride + 64 + LANE];
    }

    float xp = 1.0f;
    #pragma unroll
    for (int p = 0; p < NPTS; ++p) {
        float x0 = __shfl(pa[p], 0, 64);
        if (LANE == p) xp = x0;
    }
    {
        float bcl = fmaxf(xp, 1.0f + 1e-7f);
        float sq  = sqrtf(fmaxf(bcl * bcl - 1.0f, 1e-12f));
        float dd  = acoshf(bcl);
        xp = dd / sq;
    }
    float ma = 0.f, mb = 0.f;
    #pragma unroll
    for (int p = 0; p < NPTS; ++p) {
        float cp = rdlane(xp, p);
        ma = fmaf(pa[p], cp, ma);
        mb = fmaf(pb[p], cp, mb);
    }
    if (LANE == 0) ma = 0.f;
    ma *= (1.0f / NPTS); mb *= (1.0f / NPTS);
    float cur[2] = { ma, mb };
    w_exp0<2>(cur);
    float ca = cur[0], cb = cur[1];

    for (int it = 0; it < 10; ++it) {
        float part[NPTS];
        #pragma unroll
        for (int p = 0; p < NPTS; ++p)
            part[p] = fmaf(cb, pb[p], (LANE == 0) ? -ca * pa[p] : ca * pa[p]);
        #pragma unroll
        for (int off = 32; off; off >>= 1) {
            #pragma unroll
            for (int p = 0; p < NPTS; ++p) part[p] += __shfl_xor(part[p], off, 64);
        }
        float lp = 0.f;
        #pragma unroll
        for (int p = 0; p < NPTS; ++p) if (LANE == p) lp = part[p];
        float bb  = fmaxf(-lp, 1.0f + 1e-7f);
        float squ = sqrtf(fmaxf(bb * bb - 1.0f, 1e-12f));
        float ccv = acoshf(bb) / squ;
        float gg  = (LANE < NPTS) ? ccv * bb : 0.f;
        float gv  = wsum1(gg);
        float va = 0.f, vb = 0.f;
        #pragma unroll
        for (int p = 0; p < NPTS; ++p) {
            float cp = rdlane(ccv, p);
            va = fmaf(pa[p], cp, va);
            vb = fmaf(pb[p], cp, vb);
        }
        const float sscale = 0.5f / NPTS;
        va = (va - gv * ca) * sscale;
        vb = (vb - gv * cb) * sscale;
        float lin = wsum1(((LANE == 0) ? -va * va : va * va) + vb * vb);
        float n   = sqrtf(fmaxf(lin, 1e-12f));
        float th  = fminf(n, 10.0f);
        float ch  = coshf(th), shn = sinhf(th) / n;
        float ya = ch * ca + shn * va;
        float yb = ch * cb + shn * vb;
        float ss2 = wsum1(((LANE == 0) ? 0.f : ya * ya) + yb * yb);
        ca = (LANE == 0) ? sqrtf(1.0f + ss2) : ya;
        cb = yb;
    }
    dst[(size_t)prob * 128 + LANE] = ca;
    dst[(size_t)prob * 128 + 64 + LANE] = cb;
}

// =======================================================================
// fused decode step, rebuilt from R3-proven primitives only.
// Block = 4 rows, 256 threads; wave w owns row w for all row-ops.
// =======================================================================
__global__ __launch_bounds__(256) void k_decode_step(
    const float* __restrict__ xp_, const float* __restrict__ zl_,
    const float* __restrict__ dW0, const float* __restrict__ db0,
    const float* __restrict__ dW1, const float* __restrict__ db1,
    const float* __restrict__ dW2, const float* __restrict__ db2,
    const float* __restrict__ step_p, const float* __restrict__ alpha_p,
    const float* __restrict__ cW0, const float* __restrict__ cb0,
    const float* __restrict__ lng, const float* __restrict__ lnb,
    const float* __restrict__ cW1, const float* __restrict__ cb1,
    float* __restrict__ zn, float* __restrict__ out, int step)
{
    __shared__ float Abuf[4][256];
    __shared__ float Bbuf[4][256];
    int w = TID >> 6;
    int row0 = blockIdx.x * 4;
    size_t rb = (size_t)(row0 + w) * ED;

    float z0 = zl_[rb + LANE], z1 = zl_[rb + 64 + LANE];

    // ---- phase 1 (k_vh_w body): u1 = log0(projx(exp0(logmap(x_prev, z_last))))
    {
        float x[2] = { xp_[rb + LANE], xp_[rb + 64 + LANE] };
        float zz[2] = { z0, z1 };
        float lin  = wlinE<2>(x, zz);
        float beta = fmaxf(-lin, 1.0f + 1e-7f);
        float un   = sqrtf(fmaxf(beta * beta - 1.0f, 1e-12f));
        float sc   = acoshf(beta) / un;
        float v[2] = { sc * (zz[0] - beta * x[0]), sc * (zz[1] - beta * x[1]) };
        float ss2 = w_exp0<2>(v);
        w_log0k<2>(v, ss2);
        Abuf[w][LANE] = v[0]; Abuf[w][64 + LANE] = v[1];
    }
    __syncthreads();

    // ---- phase 2 (k_mlp4 phase B): y1 = u1 @ dW0 + db0  (128 -> 256)
    {
        float acc[4];
        #pragma unroll
        for (int r = 0; r < 4; ++r) acc[r] = db0[TID];
        for (int j = 0; j < ED; j += 4) {
            float4 uv[4];
            #pragma unroll
            for (int r = 0; r < 4; ++r) uv[r] = *(const float4*)&Abuf[r][j];
            float w0 = dW0[(size_t)(j + 0) * HD + TID];
            float w1 = dW0[(size_t)(j + 1) * HD + TID];
            float w2 = dW0[(size_t)(j + 2) * HD + TID];
            float w3 = dW0[(size_t)(j + 3) * HD + TID];
            #pragma unroll
            for (int r = 0; r < 4; ++r) {
                acc[r] = fmaf(uv[r].x, w0, acc[r]);
                acc[r] = fmaf(uv[r].y, w1, acc[r]);
                acc[r] = fmaf(uv[r].z, w2, acc[r]);
                acc[r] = fmaf(uv[r].w, w3, acc[r]);
            }
        }
        #pragma unroll
        for (int r = 0; r < 4; ++r) Bbuf[r][TID] = acc[r];
    }
    __syncthreads();

    // ---- phase 3 (k_mid pattern at E=4): u2 = l(P(e(l(P(e(y1))))))
    {
        float y[4];
        #pragma unroll
        for (int t = 0; t < 4; ++t) y[t] = Bbuf[w][t * 64 + LANE];
        float ss2 = w_exp0<4>(y);
        w_log0k<4>(y, ss2);
        ss2 = w_exp0<4>(y);
        w_log0k<4>(y, ss2);
        #pragma unroll
        for (int t = 0; t < 4; ++t) Abuf[w][t * 64 + LANE] = y[t];
    }
    __syncthreads();

    // ---- phase 4: y2 = u2 @ dW1 + db1  (256 -> 256)
    {
        float acc[4];
        #pragma unroll
        for (int r = 0; r < 4; ++r) acc[r] = db1[TID];
        for (int j = 0; j < HD; j += 4) {
            float4 uv[4];
            #pragma unroll
            for (int r = 0; r < 4; ++r) uv[r] = *(const float4*)&Abuf[r][j];
            float w0 = dW1[(size_t)(j + 0) * HD + TID];
            float w1 = dW1[(size_t)(j + 1) * HD + TID];
            float w2 = dW1[(size_t)(j + 2) * HD + TID];
            float w3 = dW1[(size_t)(j + 3) * HD + TID];
            #pragma unroll
            for (int r = 0; r < 4; ++r) {
                acc[r] = fmaf(uv[r].x, w0, acc[r]);
                acc[r] = fmaf(uv[r].y, w1, acc[r]);
                acc[r] = fmaf(uv[r].z, w2, acc[r]);
                acc[r] = fmaf(uv[r].w, w3, acc[r]);
            }
        }
        #pragma unroll
        for (int r = 0; r < 4; ++r) Bbuf[r][TID] = acc[r];
    }
    __syncthreads();

    // ---- phase 5: u3 = mid-chain(y2)
    {
        float y[4];
        #pragma unroll
        for (int t = 0; t < 4; ++t) y[t] = Bbuf[w][t * 64 + LANE];
        float ss2 = w_exp0<4>(y);
        w_log0k<4>(y, ss2);
        ss2 = w_exp0<4>(y);
        w_log0k<4>(y, ss2);
        #pragma unroll
        for (int t = 0; t < 4; ++t) Abuf[w][t * 64 + LANE] = y[t];
    }
    __syncthreads();

    // ---- phase 6: y3 = u3 @ dW2 + db2  (256 -> 128)
    {
        int col = TID & 127;
        int RB  = (TID >> 7) * 2;
        float acc[2];
        #pragma unroll
        for (int r = 0; r < 2; ++r) acc[r] = db2[col];
        for (int j = 0; j < HD; j += 4) {
            float4 uv[2];
            #pragma unroll
            for (int r = 0; r < 2; ++r) uv[r] = *(const float4*)&Abuf[RB + r][j];
            float w0 = dW2[(size_t)(j + 0) * ED + col];
            float w1 = dW2[(size_t)(j + 1) * ED + col];
            float w2 = dW2[(size_t)(j + 2) * ED + col];
            float w3 = dW2[(size_t)(j + 3) * ED + col];
            #pragma unroll
            for (int r = 0; r < 2; ++r) {
                acc[r] = fmaf(uv[r].x, w0, acc[r]);
                acc[r] = fmaf(uv[r].y, w1, acc[r]);
                acc[r] = fmaf(uv[r].z, w2, acc[r]);
                acc[r] = fmaf(uv[r].w, w3, acc[r]);
            }
        }
        #pragma unroll
        for (int r = 0; r < 2; ++r) Bbuf[RB + r][col] = acc[r];
    }
    __syncthreads();

    // ---- phase 7: vtr = l(P(e(y3))); zstep (k_zstep_w body); u4 = log0(z_next)
    {
        float y[2] = { Bbuf[w][LANE], Bbuf[w][64 + LANE] };
        float ss2v = w_exp0<2>(y);
        w_log0k<2>(y, ss2v);               // y is now v_tr

        float stp = 1.0f / (1.0f + expf(-step_p[0]));
        float a   = 1.0f / (1.0f + expf(-alpha_p[0]));
        float z[2] = { z0, z1 };
        float u[2] = { stp * y[0], stp * y[1] };
        float lin1 = wlinE<2>(u, u);
        float n1   = sqrtf(fmaxf(lin1, 1e-12f));
        float th1  = fminf(n1, 10.0f);
        float ch1  = coshf(th1), sh1 = sinhf(th1) / n1;
        float zu[2] = { ch1 * z[0] + sh1 * u[0], ch1 * z[1] + sh1 * u[1] };
        float s2 = wsum1(((LANE == 0) ? 0.f : zu[0] * zu[0]) + zu[1] * zu[1]);
        if (LANE == 0) zu[0] = sqrtf(1.0f + s2);
        float lin2 = wlinE<2>(z, zu);
        float beta = fmaxf(-lin2, 1.0f + 1e-7f);
        float un   = sqrtf(fmaxf(beta * beta - 1.0f, 1e-12f));
        float dd   = acoshf(beta);
        float sc   = dd / un;
        float g0 = (1.0f - a) * sc * (zu[0] - beta * z[0]);
        float g1 = (1.0f - a) * sc * (zu[1] - beta * z[1]);
        float n3  = sqrtf(fmaxf((1.0f - a) * (1.0f - a) * dd * dd, 1e-12f));
        float th3 = fminf(n3, 10.0f);
        float ch3 = coshf(th3), sh3 = sinhf(th3) / n3;
        float y0 = ch3 * z[0] + sh3 * g0;
        float y1 = ch3 * z[1] + sh3 * g1;
        float s3 = wsum1(((LANE == 0) ? 0.f : y0 * y0) + y1 * y1);
        if (LANE == 0) y0 = sqrtf(1.0f + s3);
        zn[rb + LANE] = y0; zn[rb + 64 + LANE] = y1;
        // u4 = logmap0(z_next) with known spatial sumsq s3
        float x0b = sqrtf(1.0f + s3);
        float dd2 = acoshf(fmaxf(x0b, 1.0f + 1e-7f));
        float sc4 = dd2 / sqrtf(fmaxf(s3, 1e-12f));
        Abuf[w][LANE]      = (LANE == 0) ? 0.f : y0 * sc4;
        Abuf[w][64 + LANE] = y1 * sc4;
    }
    __syncthreads();

    // ---- phase 8 (k_dec4 phase B): t = u4 @ cW0 + cb0  (128 -> 256)
    {
        float acc[4];
        #pragma unroll
        for (int r = 0; r < 4; ++r) acc[r] = cb0[TID];
        for (int j = 0; j < ED; j += 4) {
            float4 uv[4];
            #pragma unroll
            for (int r = 0; r < 4; ++r) uv[r] = *(const float4*)&Abuf[r][j];
            float w0 = cW0[(size_t)(j + 0) * HD + TID];
            float w1 = cW0[(size_t)(j + 1) * HD + TID];
            float w2 = cW0[(size_t)(j + 2) * HD + TID];
            float w3 = cW0[(size_t)(j + 3) * HD + TID];
            #pragma unroll
            for (int r = 0; r < 4; ++r) {
                acc[r] = fmaf(uv[r].x, w0, acc[r]);
                acc[r] = fmaf(uv[r].y, w1, acc[r]);
                acc[r] = fmaf(uv[r].z, w2, acc[r]);
                acc[r] = fmaf(uv[r].w, w3, acc[r]);
            }
        }
        #pragma unroll
        for (int r = 0; r < 4; ++r) Bbuf[r][TID] = acc[r];
    }
    __syncthreads();

    // ---- phase 9 (k_dec4 phase C): LayerNorm + exact GELU in place
    {
        float tv[4];
        #pragma unroll
        for (int t = 0; t < 4; ++t) tv[t] = Bbuf[w][t * 64 + LANE];
        float m = wsum1(tv[0] + tv[1] + tv[2] + tv[3]) * (1.0f / 256.0f);
        float c[4]; float vs = 0.f;
        #pragma unroll
        for (int t = 0; t < 4; ++t) { c[t] = tv[t] - m; vs += c[t] * c[t]; }
        float var = wsum1(vs) * (1.0f / 256.0f);
        float rstd = 1.0f / sqrtf(var + 1e-5f);
        #pragma unroll
        for (int t = 0; t < 4; ++t) {
            float g = lng[t * 64 + LANE], bb = lnb[t * 64 + LANE];
            float x = c[t] * rstd * g + bb;
            Bbuf[w][t * 64 + LANE] = 0.5f * x * (1.0f + erff(x * 0.70710678118654752f));
        }
    }
    __syncthreads();

    // ---- phase 10 (k_dec4 phase D): out = gelu(t) @ cW1 + cb1  (256 -> 504)
    {
        bool hi = (TID < 248);
        float acc0[4], acc1[4];
        #pragma unroll
        for (int r = 0; r < 4; ++r) {
            acc0[r] = cb1[TID];
            acc1[r] = hi ? cb1[TID + 256] : 0.f;
        }
        for (int j = 0; j < HD; j += 4) {
            float4 gv[4];
            #pragma unroll
            for (int r = 0; r < 4; ++r) gv[r] = *(const float4*)&Bbuf[r][j];
            #pragma unroll
            for (int k = 0; k < 4; ++k) {
                float wA = cW1[(size_t)(j + k) * 504 + TID];
                float wB = hi ? cW1[(size_t)(j + k) * 504 + TID + 256] : 0.f;
                #pragma unroll
                for (int r = 0; r < 4; ++r) {
                    float gk = (k == 0) ? gv[r].x : (k == 1) ? gv[r].y : (k == 2) ? gv[r].z : gv[r].w;
                    acc0[r] = fmaf(gk, wA, acc0[r]);
                    acc1[r] = fmaf(gk, wB, acc1[r]);
                }
            }
        }
        #pragma unroll
        for (int r = 0; r < 4; ++r) {
            float* o = out + (size_t)(row0 + r) * 2016 + (size_t)step * 504;
            o[TID] = acc0[r];
            if (hi) o[TID + 256] = acc1[r];
        }
    }
}

// ---------- launch ----------
extern "C" void kernel_launch(void* const* d_in, const int* in_sizes, int n_in,
                              void* d_out, int out_size, void* d_ws, size_t ws_size,
                              hipStream_t stream) {
    const float* trend = (const float*)d_in[0];
    const float* scrs  = (const float*)d_in[1];
    const float* sfin  = (const float*)d_in[2];
    const float* resid = (const float*)d_in[3];
    const float* eW0 = (const float*)d_in[4];
    const float* eb0 = (const float*)d_in[5];
    const float* eW1 = (const float*)d_in[6];
    const float* eb1 = (const float*)d_in[7];
    const float* eW2 = (const float*)d_in[8];
    const float* eb2 = (const float*)d_in[9];
    const float* esc = (const float*)d_in[10];
    const float* dW0 = (const float*)d_in[12];
    const float* db0 = (const float*)d_in[13];
    const float* dW1 = (const float*)d_in[14];
    const float* db1 = (const float*)d_in[15];
    const float* dW2 = (const float*)d_in[16];
    const float* db2 = (const float*)d_in[17];
    const float* alpha_p = (const float*)d_in[18];
    const float* step_p  = (const float*)d_in[19];
    const float* cW0 = (const float*)d_in[20];
    const float* cb0 = (const float*)d_in[21];
    const float* lng = (const float*)d_in[22];
    const float* lnb = (const float*)d_in[23];
    const float* cW1 = (const float*)d_in[24];
    const float* cb1 = (const float*)d_in[25];
    float* outp = (float*)d_out;

    float* w = (float*)d_ws;
    float* Y      = w;                        // 7,340,032
    float* pooled = Y + 7340032;              // 524,288
    float* comb   = pooled + 524288;          // 131,072
    float* zb0    = comb + 131072;
    float* zb1    = zb0 + 131072;
    float* zb2    = zb1 + 131072;
    float* rowAB  = zb2 + 131072;             // 114,688

    // ---- encoder (R3 structure, occupancy-tuned KC) ----
    k_prep_stats<<<NROWS / 4, 256, 0, stream>>>(trend, scrs, sfin, resid, esc, rowAB);
    k_gemm<504, 36, true><<<NROWS / 64, 256, 0, stream>>>(
        nullptr, trend, scrs, sfin, resid, rowAB, eW0, eb0, Y);
    k_mid<<<NROWS / 4, 256, 0, stream>>>(Y);
    k_gemm<128, 32, false><<<NROWS / 64, 256, 0, stream>>>(
        Y, nullptr, nullptr, nullptr, nullptr, nullptr, eW1, eb1, Y);
    k_mid<<<NROWS / 4, 256, 0, stream>>>(Y);
    k_gemm<128, 32, false><<<NROWS / 64, 256, 0, stream>>>(
        Y, nullptr, nullptr, nullptr, nullptr, nullptr, eW2, eb2, Y);
    k_post<<<NROWS / 4, 256, 0, stream>>>(Y);

    // ---- frechet pooling ----
    k_frechet_w<NSEG><<<(4 * NB) / 4, 256, 0, stream>>>(Y, (size_t)NSEG * ED, (size_t)ED, pooled);
    k_frechet_w<4><<<NB / 4, 256, 0, stream>>>(pooled, (size_t)ED, (size_t)NB * ED, comb);

    // ---- decode: one fused kernel per step ----
    const float* zl = comb;
    const float* xp = comb;
    float* zbufs[3] = {zb0, zb1, zb2};
    for (int s = 0; s < 4; ++s) {
        float* zns = zbufs[s % 3];
        k_decode_step<<<NB / 4, 256, 0, stream>>>(
            xp, zl, dW0, db0, dW1, db1, dW2, db2, step_p, alpha_p,
            cW0, cb0, lng, lnb, cW1, cb1, zns, outp, s);
        xp = zl;
        zl = zns;
    }
}

// Round 6
// 581.975 us; speedup vs baseline: 1.2174x; 1.2174x over previous
//
#include <hip/hip_runtime.h>
#include <math.h>

#define TID ((int)threadIdx.x)
#define LANE (TID & 63)

// ---------- constants ----------
#define NB 1024
#define NSEG 14
#define INP 504
#define ED 128
#define HD 256
#define ROWS (NB * NSEG)          // rows per ensemble = 14336
#define NROWS (4 * ROWS)          // 57344

// =======================================================================
// wave helpers (R5-proven)
// =======================================================================
__device__ __forceinline__ float wsum1(float v) {
    #pragma unroll
    for (int off = 32; off; off >>= 1) v += __shfl_xor(v, off, 64);
    return v;
}

__device__ __forceinline__ float rdlane(float v, int l) {
    return __int_as_float(__builtin_amdgcn_readlane(__float_as_int(v), l));
}

template<int E>
__device__ __forceinline__ float wssx(const float* v) {  // sum_{j>=1} v_j^2
    float s = (LANE == 0) ? 0.f : v[0] * v[0];
    #pragma unroll
    for (int t = 1; t < E; ++t) s += v[t] * v[t];
    return wsum1(s);
}

template<int E>
__device__ __forceinline__ float wlinE(const float* x, const float* y) {  // Minkowski
    float s = (LANE == 0) ? -x[0] * y[0] : x[0] * y[0];
    #pragma unroll
    for (int t = 1; t < E; ++t) s += x[t] * y[t];
    return wsum1(s);
}

template<int E>
__device__ __forceinline__ float w_exp0(float* v) {      // projx(safe_expmap0(v))
    float ss = wssx<E>(v);
    float n  = sqrtf(fmaxf(ss, 1e-12f));
    float th = fminf(n, 10.0f);
    float sc = sinhf(th) / n;
    #pragma unroll
    for (int t = 0; t < E; ++t) v[t] *= sc;
    float ss2 = sc * sc * ss;
    if (LANE == 0) v[0] = sqrtf(1.0f + ss2);
    return ss2;
}

template<int E>
__device__ __forceinline__ void w_log0k(float* v, float ss2) {  // logmap0, known ss2
    float x0 = sqrtf(1.0f + ss2);
    float d  = acoshf(fmaxf(x0, 1.0f + 1e-7f));
    float sc = d / sqrtf(fmaxf(ss2, 1e-12f));
    #pragma unroll
    for (int t = 0; t < E; ++t) v[t] *= sc;
    if (LANE == 0) v[0] = 0.f;
}

template<int E>
__device__ __forceinline__ void w_log0(float* v) {
    float ss = wssx<E>(v);
    float x0 = __shfl(v[0], 0, 64);
    float d  = acoshf(fmaxf(x0, 1.0f + 1e-7f));
    float sc = d / sqrtf(fmaxf(ss, 1e-12f));
    #pragma unroll
    for (int t = 0; t < E; ++t) v[t] *= sc;
    if (LANE == 0) v[0] = 0.f;
}

// =======================================================================
// K_prep_stats (R5-proven)
// =======================================================================
__global__ __launch_bounds__(256) void k_prep_stats(
    const float* __restrict__ i0, const float* __restrict__ i1,
    const float* __restrict__ i2, const float* __restrict__ i3,
    const float* __restrict__ esc, float* __restrict__ rowAB)
{
    int row = blockIdx.x * 4 + (TID >> 6);
    int e = row / ROWS;
    int r = row - e * ROWS;
    const float* src = (e == 0 ? i0 : e == 1 ? i1 : e == 2 ? i2 : i3) + (size_t)r * INP;

    float x[8];
    #pragma unroll
    for (int t = 0; t < 7; ++t) x[t] = src[64 * t + LANE];
    x[7] = (LANE < 56) ? src[448 + LANE] : 0.f;

    float s = 0.f;
    #pragma unroll
    for (int t = 0; t < 8; ++t) s += x[t];
    s = wsum1(s);
    float mu = s * (1.0f / 504.0f);
    #pragma unroll
    for (int t = 0; t < 7; ++t) x[t] -= mu;
    x[7] = (LANE < 56) ? x[7] - mu : 0.f;

    float ss = 0.f;
    #pragma unroll
    for (int t = 0; t < 8; ++t) ss += x[t] * x[t];
    ss = wsum1(ss);
    float sd  = sqrtf(ss * (1.0f / 503.0f)) + 1e-6f;
    float inv = tanhf(esc[0]) / sd;

    float x0c = __shfl(x[0], 0, 64);
    float e2 = (ss - x0c * x0c) * inv * inv;
    float n  = sqrtf(fmaxf(e2, 1e-12f));
    float th = fminf(n, 10.0f);
    float sc1 = sinhf(th) / n;
    float e3 = sc1 * sc1 * e2;
    float h0 = sqrtf(1.0f + e3);
    float d  = acoshf(fmaxf(h0, 1.0f + 1e-7f));
    float sc2 = d / sqrtf(fmaxf(e3, 1e-12f));
    float A = inv * sc1 * sc2;
    float B = -mu * A;
    if (LANE == 0) {
        rowAB[2 * row]     = A;
        rowAB[2 * row + 1] = B;
    }
}

// =======================================================================
// Tiled f32 GEMM (R5-proven)
// =======================================================================
template<int K, int KC, bool PREP>
__global__ __launch_bounds__(256) void k_gemm(
    const float* __restrict__ U,
    const float* __restrict__ i0, const float* __restrict__ i1,
    const float* __restrict__ i2, const float* __restrict__ i3,
    const float* __restrict__ rowAB,
    const float* __restrict__ Wg, const float* __restrict__ bg,
    float* __restrict__ Y)
{
    __shared__ float Ut[64][KC];
    __shared__ float Wt[KC][128];
    __shared__ float sA[64], sB[64];

    int row0 = blockIdx.x * 64;
    int e = row0 / ROWS;
    const float* Wp = Wg + (size_t)e * K * 128;

    const float* srcp;
    int rbase;
    if (PREP) {
        srcp = (e == 0 ? i0 : e == 1 ? i1 : e == 2 ? i2 : i3);
        rbase = row0 - e * ROWS;
        if (TID < 64) {
            sA[TID] = rowAB[2 * (row0 + TID)];
            sB[TID] = rowAB[2 * (row0 + TID) + 1];
        }
    } else {
        srcp = U;
        rbase = row0;
    }

    int tc = (TID & 31) * 4;
    int tr = (TID >> 5) * 8;
    float acc[8][4] = {};

    for (int kc = 0; kc < K; kc += KC) {
        __syncthreads();
        for (int idx = TID; idx < 64 * (KC / 4); idx += 256) {
            int r  = idx / (KC / 4);
            int kq = idx - r * (KC / 4);
            float4 v = *(const float4*)&srcp[(size_t)(rbase + r) * K + kc + kq * 4];
            if (PREP) {
                float a = sA[r], bb = sB[r];
                v.x = v.x * a + bb; v.y = v.y * a + bb;
                v.z = v.z * a + bb; v.w = v.w * a + bb;
                if (kc == 0 && kq == 0) v.x = 0.f;
            }
            *(float4*)&Ut[r][kq * 4] = v;
        }
        for (int idx = TID; idx < KC * 32; idx += 256) {
            int k = idx >> 5;
            int c = (idx & 31) * 4;
            *(float4*)&Wt[k][c] = *(const float4*)&Wp[(size_t)(kc + k) * 128 + c];
        }
        __syncthreads();
        for (int k = 0; k < KC; k += 4) {
            float4 b0 = *(const float4*)&Wt[k + 0][tc];
            float4 b1 = *(const float4*)&Wt[k + 1][tc];
            float4 b2 = *(const float4*)&Wt[k + 2][tc];
            float4 b3 = *(const float4*)&Wt[k + 3][tc];
            #pragma unroll
            for (int i = 0; i < 8; ++i) {
                float4 a = *(const float4*)&Ut[tr + i][k];
                acc[i][0] += a.x * b0.x; acc[i][1] += a.x * b0.y; acc[i][2] += a.x * b0.z; acc[i][3] += a.x * b0.w;
                acc[i][0] += a.y * b1.x; acc[i][1] += a.y * b1.y; acc[i][2] += a.y * b1.z; acc[i][3] += a.y * b1.w;
                acc[i][0] += a.z * b2.x; acc[i][1] += a.z * b2.y; acc[i][2] += a.z * b2.z; acc[i][3] += a.z * b2.w;
                acc[i][0] += a.w * b3.x; acc[i][1] += a.w * b3.y; acc[i][2] += a.w * b3.z; acc[i][3] += a.w * b3.w;
            }
        }
    }

    float4 bias = *(const float4*)&bg[e * 128 + tc];
    #pragma unroll
    for (int i = 0; i < 8; ++i) {
        float4 o;
        o.x = acc[i][0] + bias.x; o.y = acc[i][1] + bias.y;
        o.z = acc[i][2] + bias.z; o.w = acc[i][3] + bias.w;
        *(float4*)&Y[(size_t)(row0 + tr + i) * 128 + tc] = o;
    }
}

// =======================================================================
// inter-GEMM row chains (R5-proven)
// =======================================================================
__global__ __launch_bounds__(256) void k_mid(float* __restrict__ Y) {
    int row = blockIdx.x * 4 + (TID >> 6);
    size_t base = (size_t)row * 128;
    float v[2] = { Y[base + LANE], Y[base + 64 + LANE] };
    float ss2 = w_exp0<2>(v);
    w_log0k<2>(v, ss2);
    ss2 = w_exp0<2>(v);
    w_log0k<2>(v, ss2);
    Y[base + LANE] = v[0]; Y[base + 64 + LANE] = v[1];
}

__global__ __launch_bounds__(256) void k_post(float* __restrict__ Y) {
    int row = blockIdx.x * 4 + (TID >> 6);
    size_t base = (size_t)row * 128;
    float v[2] = { Y[base + LANE], Y[base + 64 + LANE] };
    w_exp0<2>(v);
    Y[base + LANE] = v[0]; Y[base + 64 + LANE] = v[1];
}

// =======================================================================
// frechet mean (R5-proven)
// =======================================================================
template<int NPTS>
__global__ __launch_bounds__(256) void k_frechet_w(
    const float* __restrict__ src, size_t blk_stride, size_t p_stride,
    float* __restrict__ dst)
{
    int prob = blockIdx.x * 4 + (TID >> 6);
    const float* base = src + (size_t)prob * blk_stride;
    float pa[NPTS], pb[NPTS];
    #pragma unroll
    for (int p = 0; p < NPTS; ++p) {
        pa[p] = base[(size_t)p * p_stride + LANE];
        pb[p] = base[(size_t)p * p_stride + 64 + LANE];
    }

    float xp = 1.0f;
    #pragma unroll
    for (int p = 0; p < NPTS; ++p) {
        float x0 = __shfl(pa[p], 0, 64);
        if (LANE == p) xp = x0;
    }
    {
        float bcl = fmaxf(xp, 1.0f + 1e-7f);
        float sq  = sqrtf(fmaxf(bcl * bcl - 1.0f, 1e-12f));
        float dd  = acoshf(bcl);
        xp = dd / sq;
    }
    float ma = 0.f, mb = 0.f;
    #pragma unroll
    for (int p = 0; p < NPTS; ++p) {
        float cp = rdlane(xp, p);
        ma = fmaf(pa[p], cp, ma);
        mb = fmaf(pb[p], cp, mb);
    }
    if (LANE == 0) ma = 0.f;
    ma *= (1.0f / NPTS); mb *= (1.0f / NPTS);
    float cur[2] = { ma, mb };
    w_exp0<2>(cur);
    float ca = cur[0], cb = cur[1];

    for (int it = 0; it < 10; ++it) {
        float part[NPTS];
        #pragma unroll
        for (int p = 0; p < NPTS; ++p)
            part[p] = fmaf(cb, pb[p], (LANE == 0) ? -ca * pa[p] : ca * pa[p]);
        #pragma unroll
        for (int off = 32; off; off >>= 1) {
            #pragma unroll
            for (int p = 0; p < NPTS; ++p) part[p] += __shfl_xor(part[p], off, 64);
        }
        float lp = 0.f;
        #pragma unroll
        for (int p = 0; p < NPTS; ++p) if (LANE == p) lp = part[p];
        float bb  = fmaxf(-lp, 1.0f + 1e-7f);
        float squ = sqrtf(fmaxf(bb * bb - 1.0f, 1e-12f));
        float ccv = acoshf(bb) / squ;
        float gg  = (LANE < NPTS) ? ccv * bb : 0.f;
        float gv  = wsum1(gg);
        float va = 0.f, vb = 0.f;
        #pragma unroll
        for (int p = 0; p < NPTS; ++p) {
            float cp = rdlane(ccv, p);
            va = fmaf(pa[p], cp, va);
            vb = fmaf(pb[p], cp, vb);
        }
        const float sscale = 0.5f / NPTS;
        va = (va - gv * ca) * sscale;
        vb = (vb - gv * cb) * sscale;
        float lin = wsum1(((LANE == 0) ? -va * va : va * va) + vb * vb);
        float n   = sqrtf(fmaxf(lin, 1e-12f));
        float th  = fminf(n, 10.0f);
        float ch  = coshf(th), shn = sinhf(th) / n;
        float ya = ch * ca + shn * va;
        float yb = ch * cb + shn * vb;
        float ss2 = wsum1(((LANE == 0) ? 0.f : ya * ya) + yb * yb);
        ca = (LANE == 0) ? sqrtf(1.0f + ss2) : ya;
        cb = yb;
    }
    dst[(size_t)prob * 128 + LANE] = ca;
    dst[(size_t)prob * 128 + 64 + LANE] = cb;
}

// =======================================================================
// fused decode step v2: 512 threads (8 waves), 4 rows/block, 256 blocks.
// K-split GEMMs + uT[k][4] float4 broadcasts. Math identical to R5.
//   uT[k*4 + r] : input vector element k of row r (b128 broadcast read)
//   Bbuf[r][col]: GEMM outputs for row-op consumption
// =======================================================================
__global__ __launch_bounds__(512) void k_decode_step(
    const float* __restrict__ xp_, const float* __restrict__ zl_,
    const float* __restrict__ dW0, const float* __restrict__ db0,
    const float* __restrict__ dW1, const float* __restrict__ db1,
    const float* __restrict__ dW2, const float* __restrict__ db2,
    const float* __restrict__ step_p, const float* __restrict__ alpha_p,
    const float* __restrict__ cW0, const float* __restrict__ cb0,
    const float* __restrict__ lng, const float* __restrict__ lnb,
    const float* __restrict__ cW1, const float* __restrict__ cb1,
    float* __restrict__ zn, float* __restrict__ out, int step)
{
    __shared__ float uT[256 * 4];        // 4 KB
    __shared__ float Bbuf[4][256];       // 4 KB
    __shared__ float part[6 * 256];      // 6 KB (union: [4][256] / [3][4][128])
    int w = TID >> 6;
    int row0 = blockIdx.x * 4;

    float z0 = 0.f, z1 = 0.f;
    size_t rb = (size_t)(row0 + (w & 3)) * ED;

    // ---- phase 1 (waves 0-3): u1 = log0(projx(exp0(logmap(xp, zl)))) -> uT
    if (w < 4) {
        z0 = zl_[rb + LANE]; z1 = zl_[rb + 64 + LANE];
        float x[2] = { xp_[rb + LANE], xp_[rb + 64 + LANE] };
        float zz[2] = { z0, z1 };
        float lin  = wlinE<2>(x, zz);
        float beta = fmaxf(-lin, 1.0f + 1e-7f);
        float un   = sqrtf(fmaxf(beta * beta - 1.0f, 1e-12f));
        float sc   = acoshf(beta) / un;
        float v[2] = { sc * (zz[0] - beta * x[0]), sc * (zz[1] - beta * x[1]) };
        float ss2 = w_exp0<2>(v);
        w_log0k<2>(v, ss2);
        uT[LANE * 4 + w]        = v[0];
        uT[(64 + LANE) * 4 + w] = v[1];
    }
    __syncthreads();

    // ---- phase 2: y1 = u1 @ dW0 + db0  (K=128 -> 256), K-split 2
    {
        int kh = TID >> 8;          // 0: waves 0-3, 1: waves 4-7
        int col = TID & 255;
        int k0 = kh * 64;
        float a0 = 0.f, a1 = 0.f, a2 = 0.f, a3 = 0.f;
        #pragma unroll 8
        for (int i = 0; i < 64; ++i) {
            float4 uv = *(const float4*)&uT[(k0 + i) * 4];
            float wv = dW0[(size_t)(k0 + i) * HD + col];
            a0 = fmaf(uv.x, wv, a0); a1 = fmaf(uv.y, wv, a1);
            a2 = fmaf(uv.z, wv, a2); a3 = fmaf(uv.w, wv, a3);
        }
        if (kh == 1) {
            part[0 * 256 + col] = a0; part[1 * 256 + col] = a1;
            part[2 * 256 + col] = a2; part[3 * 256 + col] = a3;
        }
        __syncthreads();
        if (kh == 0) {
            float b = db0[col];
            Bbuf[0][col] = a0 + part[0 * 256 + col] + b;
            Bbuf[1][col] = a1 + part[1 * 256 + col] + b;
            Bbuf[2][col] = a2 + part[2 * 256 + col] + b;
            Bbuf[3][col] = a3 + part[3 * 256 + col] + b;
        }
    }
    __syncthreads();

    // ---- phase 3 (waves 0-3): u2 = l(P(e(l(P(e(y1)))))) -> uT
    if (w < 4) {
        float y[4];
        #pragma unroll
        for (int t = 0; t < 4; ++t) y[t] = Bbuf[w][t * 64 + LANE];
        float ss2 = w_exp0<4>(y);
        w_log0k<4>(y, ss2);
        ss2 = w_exp0<4>(y);
        w_log0k<4>(y, ss2);
        #pragma unroll
        for (int t = 0; t < 4; ++t) uT[(t * 64 + LANE) * 4 + w] = y[t];
    }
    __syncthreads();

    // ---- phase 4: y2 = u2 @ dW1 + db1  (K=256 -> 256), K-split 2
    {
        int kh = TID >> 8;
        int col = TID & 255;
        int k0 = kh * 128;
        float a0 = 0.f, a1 = 0.f, a2 = 0.f, a3 = 0.f;
        #pragma unroll 8
        for (int i = 0; i < 128; ++i) {
            float4 uv = *(const float4*)&uT[(k0 + i) * 4];
            float wv = dW1[(size_t)(k0 + i) * HD + col];
            a0 = fmaf(uv.x, wv, a0); a1 = fmaf(uv.y, wv, a1);
            a2 = fmaf(uv.z, wv, a2); a3 = fmaf(uv.w, wv, a3);
        }
        if (kh == 1) {
            part[0 * 256 + col] = a0; part[1 * 256 + col] = a1;
            part[2 * 256 + col] = a2; part[3 * 256 + col] = a3;
        }
        __syncthreads();
        if (kh == 0) {
            float b = db1[col];
            Bbuf[0][col] = a0 + part[0 * 256 + col] + b;
            Bbuf[1][col] = a1 + part[1 * 256 + col] + b;
            Bbuf[2][col] = a2 + part[2 * 256 + col] + b;
            Bbuf[3][col] = a3 + part[3 * 256 + col] + b;
        }
    }
    __syncthreads();

    // ---- phase 5 (waves 0-3): u3 = mid-chain(y2) -> uT
    if (w < 4) {
        float y[4];
        #pragma unroll
        for (int t = 0; t < 4; ++t) y[t] = Bbuf[w][t * 64 + LANE];
        float ss2 = w_exp0<4>(y);
        w_log0k<4>(y, ss2);
        ss2 = w_exp0<4>(y);
        w_log0k<4>(y, ss2);
        #pragma unroll
        for (int t = 0; t < 4; ++t) uT[(t * 64 + LANE) * 4 + w] = y[t];
    }
    __syncthreads();

    // ---- phase 6: y3 = u3 @ dW2 + db2  (K=256 -> 128), K-split 4
    {
        int kq = TID >> 7;          // 0..3, wave-pair uniform
        int col = TID & 127;
        int k0 = kq * 64;
        float a0 = 0.f, a1 = 0.f, a2 = 0.f, a3 = 0.f;
        #pragma unroll 8
        for (int i = 0; i < 64; ++i) {
            float4 uv = *(const float4*)&uT[(k0 + i) * 4];
            float wv = dW2[(size_t)(k0 + i) * ED + col];
            a0 = fmaf(uv.x, wv, a0); a1 = fmaf(uv.y, wv, a1);
            a2 = fmaf(uv.z, wv, a2); a3 = fmaf(uv.w, wv, a3);
        }
        if (kq >= 1) {
            float* pp = &part[((kq - 1) * 4) * 128];
            pp[0 * 128 + col] = a0; pp[1 * 128 + col] = a1;
            pp[2 * 128 + col] = a2; pp[3 * 128 + col] = a3;
        }
        __syncthreads();
        if (kq == 0) {
            float b = db2[col];
            #pragma unroll
            for (int r = 0; r < 4; ++r) {
                float acc = (r == 0) ? a0 : (r == 1) ? a1 : (r == 2) ? a2 : a3;
                acc += part[(0 * 4 + r) * 128 + col];
                acc += part[(1 * 4 + r) * 128 + col];
                acc += part[(2 * 4 + r) * 128 + col];
                Bbuf[r][col] = acc + b;
            }
        }
    }
    __syncthreads();

    // ---- phase 7 (waves 0-3): vtr = l(P(e(y3))); zstep; u4 = log0(z_next) -> uT
    if (w < 4) {
        float y[2] = { Bbuf[w][LANE], Bbuf[w][64 + LANE] };
        float ss2v = w_exp0<2>(y);
        w_log0k<2>(y, ss2v);               // y is now v_tr

        float stp = 1.0f / (1.0f + expf(-step_p[0]));
        float a   = 1.0f / (1.0f + expf(-alpha_p[0]));
        float z[2] = { z0, z1 };
        float u[2] = { stp * y[0], stp * y[1] };
        float lin1 = wlinE<2>(u, u);
        float n1   = sqrtf(fmaxf(lin1, 1e-12f));
        float th1  = fminf(n1, 10.0f);
        float ch1  = coshf(th1), sh1 = sinhf(th1) / n1;
        float zu[2] = { ch1 * z[0] + sh1 * u[0], ch1 * z[1] + sh1 * u[1] };
        float s2 = wsum1(((LANE == 0) ? 0.f : zu[0] * zu[0]) + zu[1] * zu[1]);
        if (LANE == 0) zu[0] = sqrtf(1.0f + s2);
        float lin2 = wlinE<2>(z, zu);
        float beta = fmaxf(-lin2, 1.0f + 1e-7f);
        float un   = sqrtf(fmaxf(beta * beta - 1.0f, 1e-12f));
        float dd   = acoshf(beta);
        float sc   = dd / un;
        float g0 = (1.0f - a) * sc * (zu[0] - beta * z[0]);
        float g1 = (1.0f - a) * sc * (zu[1] - beta * z[1]);
        float n3  = sqrtf(fmaxf((1.0f - a) * (1.0f - a) * dd * dd, 1e-12f));
        float th3 = fminf(n3, 10.0f);
        float ch3 = coshf(th3), sh3 = sinhf(th3) / n3;
        float y0 = ch3 * z[0] + sh3 * g0;
        float y1 = ch3 * z[1] + sh3 * g1;
        float s3 = wsum1(((LANE == 0) ? 0.f : y0 * y0) + y1 * y1);
        if (LANE == 0) y0 = sqrtf(1.0f + s3);
        zn[rb + LANE] = y0; zn[rb + 64 + LANE] = y1;
        float x0b = sqrtf(1.0f + s3);
        float dd2 = acoshf(fmaxf(x0b, 1.0f + 1e-7f));
        float sc4 = dd2 / sqrtf(fmaxf(s3, 1e-12f));
        uT[LANE * 4 + w]        = (LANE == 0) ? 0.f : y0 * sc4;
        uT[(64 + LANE) * 4 + w] = y1 * sc4;
    }
    __syncthreads();

    // ---- phase 8: t = u4 @ cW0 + cb0  (K=128 -> 256), K-split 2
    {
        int kh = TID >> 8;
        int col = TID & 255;
        int k0 = kh * 64;
        float a0 = 0.f, a1 = 0.f, a2 = 0.f, a3 = 0.f;
        #pragma unroll 8
        for (int i = 0; i < 64; ++i) {
            float4 uv = *(const float4*)&uT[(k0 + i) * 4];
            float wv = cW0[(size_t)(k0 + i) * HD + col];
            a0 = fmaf(uv.x, wv, a0); a1 = fmaf(uv.y, wv, a1);
            a2 = fmaf(uv.z, wv, a2); a3 = fmaf(uv.w, wv, a3);
        }
        if (kh == 1) {
            part[0 * 256 + col] = a0; part[1 * 256 + col] = a1;
            part[2 * 256 + col] = a2; part[3 * 256 + col] = a3;
        }
        __syncthreads();
        if (kh == 0) {
            float b = cb0[col];
            Bbuf[0][col] = a0 + part[0 * 256 + col] + b;
            Bbuf[1][col] = a1 + part[1 * 256 + col] + b;
            Bbuf[2][col] = a2 + part[2 * 256 + col] + b;
            Bbuf[3][col] = a3 + part[3 * 256 + col] + b;
        }
    }
    __syncthreads();

    // ---- phase 9 (waves 0-3): LayerNorm + exact GELU -> uT
    if (w < 4) {
        float tv[4];
        #pragma unroll
        for (int t = 0; t < 4; ++t) tv[t] = Bbuf[w][t * 64 + LANE];
        float m = wsum1(tv[0] + tv[1] + tv[2] + tv[3]) * (1.0f / 256.0f);
        float c[4]; float vs = 0.f;
        #pragma unroll
        for (int t = 0; t < 4; ++t) { c[t] = tv[t] - m; vs += c[t] * c[t]; }
        float var = wsum1(vs) * (1.0f / 256.0f);
        float rstd = 1.0f / sqrtf(var + 1e-5f);
        #pragma unroll
        for (int t = 0; t < 4; ++t) {
            float g = lng[t * 64 + LANE], bb = lnb[t * 64 + LANE];
            float x = c[t] * rstd * g + bb;
            uT[(t * 64 + LANE) * 4 + w] = 0.5f * x * (1.0f + erff(x * 0.70710678118654752f));
        }
    }
    __syncthreads();

    // ---- phase 10: out = gelu(t) @ cW1 + cb1  (K=256 -> 504), col-per-thread
    {
        int col = TID;
        bool ok = (col < 504);
        float a0 = 0.f, a1 = 0.f, a2 = 0.f, a3 = 0.f;
        #pragma unroll 8
        for (int i = 0; i < 256; ++i) {
            float4 uv = *(const float4*)&uT[i * 4];
            float wv = ok ? cW1[(size_t)i * 504 + col] : 0.f;
            a0 = fmaf(uv.x, wv, a0); a1 = fmaf(uv.y, wv, a1);
            a2 = fmaf(uv.z, wv, a2); a3 = fmaf(uv.w, wv, a3);
        }
        if (ok) {
            float b = cb1[col];
            size_t ob = (size_t)row0 * 2016 + (size_t)step * 504 + col;
            out[ob]            = a0 + b;
            out[ob + 2016]     = a1 + b;
            out[ob + 2 * 2016] = a2 + b;
            out[ob + 3 * 2016] = a3 + b;
        }
    }
}

// ---------- launch ----------
extern "C" void kernel_launch(void* const* d_in, const int* in_sizes, int n_in,
                              void* d_out, int out_size, void* d_ws, size_t ws_size,
                              hipStream_t stream) {
    const float* trend = (const float*)d_in[0];
    const float* scrs  = (const float*)d_in[1];
    const float* sfin  = (const float*)d_in[2];
    const float* resid = (const float*)d_in[3];
    const float* eW0 = (const float*)d_in[4];
    const float* eb0 = (const float*)d_in[5];
    const float* eW1 = (const float*)d_in[6];
    const float* eb1 = (const float*)d_in[7];
    const float* eW2 = (const float*)d_in[8];
    const float* eb2 = (const float*)d_in[9];
    const float* esc = (const float*)d_in[10];
    const float* dW0 = (const float*)d_in[12];
    const float* db0 = (const float*)d_in[13];
    const float* dW1 = (const float*)d_in[14];
    const float* db1 = (const float*)d_in[15];
    const float* dW2 = (const float*)d_in[16];
    const float* db2 = (const float*)d_in[17];
    const float* alpha_p = (const float*)d_in[18];
    const float* step_p  = (const float*)d_in[19];
    const float* cW0 = (const float*)d_in[20];
    const float* cb0 = (const float*)d_in[21];
    const float* lng = (const float*)d_in[22];
    const float* lnb = (const float*)d_in[23];
    const float* cW1 = (const float*)d_in[24];
    const float* cb1 = (const float*)d_in[25];
    float* outp = (float*)d_out;

    float* w = (float*)d_ws;
    float* Y      = w;                        // 7,340,032
    float* pooled = Y + 7340032;              // 524,288
    float* comb   = pooled + 524288;          // 131,072
    float* zb0    = comb + 131072;
    float* zb1    = zb0 + 131072;
    float* zb2    = zb1 + 131072;
    float* rowAB  = zb2 + 131072;             // 114,688

    // ---- encoder (R5 structure) ----
    k_prep_stats<<<NROWS / 4, 256, 0, stream>>>(trend, scrs, sfin, resid, esc, rowAB);
    k_gemm<504, 36, true><<<NROWS / 64, 256, 0, stream>>>(
        nullptr, trend, scrs, sfin, resid, rowAB, eW0, eb0, Y);
    k_mid<<<NROWS / 4, 256, 0, stream>>>(Y);
    k_gemm<128, 32, false><<<NROWS / 64, 256, 0, stream>>>(
        Y, nullptr, nullptr, nullptr, nullptr, nullptr, eW1, eb1, Y);
    k_mid<<<NROWS / 4, 256, 0, stream>>>(Y);
    k_gemm<128, 32, false><<<NROWS / 64, 256, 0, stream>>>(
        Y, nullptr, nullptr, nullptr, nullptr, nullptr, eW2, eb2, Y);
    k_post<<<NROWS / 4, 256, 0, stream>>>(Y);

    // ---- frechet pooling ----
    k_frechet_w<NSEG><<<(4 * NB) / 4, 256, 0, stream>>>(Y, (size_t)NSEG * ED, (size_t)ED, pooled);
    k_frechet_w<4><<<NB / 4, 256, 0, stream>>>(pooled, (size_t)ED, (size_t)NB * ED, comb);

    // ---- decode: one fused kernel per step (512 threads, K-split) ----
    const float* zl = comb;
    const float* xp = comb;
    float* zbufs[3] = {zb0, zb1, zb2};
    for (int s = 0; s < 4; ++s) {
        float* zns = zbufs[s % 3];
        k_decode_step<<<NB / 4, 512, 0, stream>>>(
            xp, zl, dW0, db0, dW1, db1, dW2, db2, step_p, alpha_p,
            cW0, cb0, lng, lnb, cW1, cb1, zns, outp, s);
        xp = zl;
        zl = zns;
    }
}